// Round 1
// baseline (746.543 us; speedup 1.0000x reference)
//
#include <hip/hip_runtime.h>
#include <cmath>

#define NB 256      // batch
#define NT_ 2048    // timesteps
#define DIN 64
#define DH 128
#define TT 64       // time tile
#define NTILES (NT_ / TT)   // 32

// LDS budget: x double buffer 2*64*64*4 = 32 KB, ff tile 64*128*4 = 32 KB -> 64 KB total

typedef const __attribute__((address_space(1))) void gptr_t;
typedef __attribute__((address_space(3))) void lptr_t;

__global__ __launch_bounds__(256) void snn_fused_kernel(
    const float* __restrict__ x, const float* __restrict__ W,
    const float* __restrict__ bias, float* __restrict__ out)
{
    __shared__ float xs[2][TT * DIN];   // 2 x 4096 floats
    __shared__ float ffs[TT * DH];      // 8192 floats

    const int tid  = threadIdx.x;
    const int b    = blockIdx.x;
    const int h    = tid & (DH - 1);    // 0..127
    const int tg   = tid >> 7;          // 0 or 1 (wave-pair uniform)
    const int lane = tid & 63;
    const int wv   = tid >> 6;          // wave id 0..3

    // --- load W row (64 floats) into registers; bias ---
    float4 w4[16];
    const float4* Wrow = (const float4*)(W + h * DIN);
    #pragma unroll
    for (int kk = 0; kk < 16; ++kk) w4[kk] = Wrow[kk];
    const float bh = bias[h];

    const float* xb = x + (size_t)b * NT_ * DIN;
    float* outb = out + (size_t)b * NT_ * DH;

    // --- preload x tile 0 via async global->LDS (wave-contiguous chunks) ---
    #pragma unroll
    for (int p = 0; p < 4; ++p) {
        int off = (wv * 4 + p) * 256 + lane * 4;   // float offset, 16B per lane
        __builtin_amdgcn_global_load_lds((gptr_t*)(xb + off),
                                         (lptr_t*)(&xs[0][off]), 16, 0, 0);
    }
    __syncthreads();

    float mem = 0.f, spk = 0.f;

    for (int tile = 0; tile < NTILES; ++tile) {
        const int buf = tile & 1;

        // --- async prefetch next x tile into other buffer ---
        if (tile + 1 < NTILES) {
            const float* gsrc = xb + (size_t)(tile + 1) * TT * DIN;
            #pragma unroll
            for (int p = 0; p < 4; ++p) {
                int off = (wv * 4 + p) * 256 + lane * 4;
                __builtin_amdgcn_global_load_lds((gptr_t*)(gsrc + off),
                                                 (lptr_t*)(&xs[buf ^ 1][off]), 16, 0, 0);
            }
        }

        // --- compute ff tile: each thread does 32 dot-64s for (t = tg+2j, h) ---
        #pragma unroll 2
        for (int j = 0; j < TT / 2; ++j) {
            const int t = tg + 2 * j;   // wave-uniform -> LDS broadcast reads
            const float4* xt = (const float4*)&xs[buf][t * DIN];
            float a0 = 0.f, a1 = 0.f, a2 = 0.f, a3 = 0.f;
            #pragma unroll
            for (int kk = 0; kk < 16; ++kk) {
                float4 xv = xt[kk];
                a0 = fmaf(xv.x, w4[kk].x, a0);
                a1 = fmaf(xv.y, w4[kk].y, a1);
                a2 = fmaf(xv.z, w4[kk].z, a2);
                a3 = fmaf(xv.w, w4[kk].w, a3);
            }
            ffs[t * DH + h] = (a0 + a1) + (a2 + a3) + bh;
        }
        __syncthreads();   // ff ready (also drains prefetch vmcnt)

        // --- sequential scan over this tile (threads 0..127, one per h) ---
        if (tid < DH) {
            float* op = outb + (size_t)(tile * TT) * DH + tid;
            #pragma unroll 4
            for (int tt = 0; tt < TT; ++tt) {
                float f = ffs[tt * DH + tid];
                mem = fmaf(0.9f, mem, f - spk);
                // sigmoid(5*(mem-1)) = 1/(1+2^(-5*log2e*(mem-1)))
                float e = __builtin_amdgcn_exp2f(-7.213475204444817f * (mem - 1.f));
                spk = __builtin_amdgcn_rcpf(1.f + e);
                op[(size_t)tt * DH] = spk;
            }
        }
        __syncthreads();   // scan done reading ffs; next tile may overwrite
    }
}

extern "C" void kernel_launch(void* const* d_in, const int* in_sizes, int n_in,
                              void* d_out, int out_size, void* d_ws, size_t ws_size,
                              hipStream_t stream) {
    const float* x  = (const float*)d_in[0];
    const float* W  = (const float*)d_in[1];
    const float* bb = (const float*)d_in[2];
    float* out = (float*)d_out;
    snn_fused_kernel<<<dim3(NB), dim3(256), 0, stream>>>(x, W, bb, out);
}

// Round 2
// 528.513 us; speedup vs baseline: 1.4125x; 1.4125x over previous
//
#include <hip/hip_runtime.h>

#define NB 256       // batch
#define NT_ 2048     // timesteps
#define DIN 64
#define DH 128
#define HB 64        // h-channels per block (h-split: 2 blocks per batch)
#define TT 32        // time tile
#define NTILES (NT_ / TT)   // 64

// LDS: xs 2*32*64*4 = 16 KB, ffs 2*32*64*4 = 16 KB -> 32 KB/block, 2 blocks/CU fits.

typedef const __attribute__((address_space(1))) void gptr_t;
typedef __attribute__((address_space(3))) void lptr_t;

__device__ __forceinline__ void scan_tile(const float* ffs_buf, float& mem, float& spk,
                                          float* op, int t0, int lane) {
    #pragma unroll
    for (int tt = 0; tt < TT; ++tt) {
        float f = ffs_buf[tt * HB + lane];
        mem = fmaf(0.9f, mem, f - spk);
        // sigmoid(5*(mem-1)) = 1/(1+2^(-5*log2e*(mem-1)))
        float e = __builtin_amdgcn_exp2f(-7.213475204444817f * (mem - 1.f));
        spk = __builtin_amdgcn_rcpf(1.f + e);
        op[(size_t)(t0 + tt) * DH] = spk;
    }
}

__global__ __launch_bounds__(576) void snn_fused_kernel(
    const float* __restrict__ x, const float* __restrict__ W,
    const float* __restrict__ bias, float* __restrict__ out)
{
    __shared__ float xs[2][TT * DIN];   // staged x tiles
    __shared__ float ffs[2][TT * HB];   // produced ff tiles

    const int tid   = threadIdx.x;
    const int wv    = tid >> 6;         // 0..8 (waves 0-7: GEMM, wave 8: scan)
    const int lane  = tid & 63;
    const int b     = blockIdx.x >> 1;
    const int hhalf = blockIdx.x & 1;

    const float* xb = x + (size_t)b * NT_ * DIN;

    if (wv < 8) {
        // ---------------- producer: GEMM waves ----------------
        // each thread: one h (= hhalf*64 + lane), 4 timesteps (t = wv*4 + i)
        const int h = hhalf * HB + lane;
        float4 w4[16];
        const float4* Wrow = (const float4*)(W + h * DIN);
        #pragma unroll
        for (int kk = 0; kk < 16; ++kk) w4[kk] = Wrow[kk];
        const float bh = bias[h];

        const int loff = tid * 4;   // float offset into tile (512 thr * 16B = 8KB tile)

        // preload x tile 0 (async global->LDS, wave-uniform base + lane*16B)
        __builtin_amdgcn_global_load_lds((gptr_t*)(xb + loff),
                                         (lptr_t*)(&xs[0][loff]), 16, 0, 0);
        __syncthreads();   // [barrier 0]

        for (int it = 0; it < NTILES; ++it) {
            const int buf = it & 1;
            // async prefetch next x tile into other buffer (drained by end barrier)
            if (it + 1 < NTILES) {
                __builtin_amdgcn_global_load_lds(
                    (gptr_t*)(xb + (size_t)(it + 1) * TT * DIN + loff),
                    (lptr_t*)(&xs[buf ^ 1][loff]), 16, 0, 0);
            }
            // compute ff for 4 wave-uniform timesteps (broadcast LDS reads)
            #pragma unroll
            for (int i = 0; i < 4; ++i) {
                const int t = wv * 4 + i;
                const float4* xt = (const float4*)&xs[buf][t * DIN];
                float a0 = 0.f, a1 = 0.f, a2 = 0.f, a3 = 0.f;
                #pragma unroll
                for (int kk = 0; kk < 16; ++kk) {
                    float4 xv = xt[kk];
                    a0 = fmaf(xv.x, w4[kk].x, a0);
                    a1 = fmaf(xv.y, w4[kk].y, a1);
                    a2 = fmaf(xv.z, w4[kk].z, a2);
                    a3 = fmaf(xv.w, w4[kk].w, a3);
                }
                ffs[buf][t * HB + lane] = (a0 + a1) + (a2 + a3) + bh;
            }
            __syncthreads();   // [barrier 1+it] ff tile it published
        }
    } else {
        // ---------------- consumer: scan wave ----------------
        float mem = 0.f, spk = 0.f;
        float* op = out + (size_t)b * NT_ * DH + hhalf * HB + lane;

        __syncthreads();   // [barrier 0]
        for (int it = 0; it < NTILES; ++it) {
            if (it > 0) {
                scan_tile(ffs[(it - 1) & 1], mem, spk, op, (it - 1) * TT, lane);
            }
            __syncthreads();   // [barrier 1+it]
        }
        // drain: last tile (GEMM waves have exited; no barrier needed)
        scan_tile(ffs[(NTILES - 1) & 1], mem, spk, op, (NTILES - 1) * TT, lane);
    }
}

extern "C" void kernel_launch(void* const* d_in, const int* in_sizes, int n_in,
                              void* d_out, int out_size, void* d_ws, size_t ws_size,
                              hipStream_t stream) {
    const float* x  = (const float*)d_in[0];
    const float* W  = (const float*)d_in[1];
    const float* bb = (const float*)d_in[2];
    float* out = (float*)d_out;
    snn_fused_kernel<<<dim3(NB * 2), dim3(576), 0, stream>>>(x, W, bb, out);
}